// Round 6
// baseline (4155.183 us; speedup 1.0000x reference)
//
#include <hip/hip_runtime.h>
#include <stdint.h>

#define NN 100000
#define MM 500000
#define FD 128
#define KK 256
#define NHEADS 3
#define NTILES 3907

typedef __attribute__((ext_vector_type(8))) __bf16 bf16x8;
typedef __attribute__((ext_vector_type(4))) float floatx4;

__device__ __forceinline__ unsigned short f2bf(float f) {
    union { float f; uint32_t i; } c; c.f = f;
    uint32_t i = c.i;
    return (unsigned short)((i + 0x7FFFu + ((i >> 16) & 1u)) >> 16);
}
__device__ __forceinline__ float silu(float a) { return a / (1.f + __expf(-a)); }
__device__ __forceinline__ float fin(float v) {
    return (v == v && fabsf(v) < 1e30f) ? v : 0.f;
}

// =================== zero ===================
__global__ void k_zero(float* __restrict__ p, int nwords) {
    int i = blockIdx.x * 256 + threadIdx.x;
    if (i < nwords) p[i] = 0.f;
}

// =================== cast x (fp32) -> xb (bf16) ===================
__global__ void k_castx(const float* __restrict__ x, unsigned short* __restrict__ xb) {
    int i = blockIdx.x * 256 + threadIdx.x;   // pair index
    if (i < NN * FD / 2) {
        float2 v = ((const float2*)x)[i];
        uint32_t p = (uint32_t)f2bf(v.x) | ((uint32_t)f2bf(v.y) << 16);
        ((uint32_t*)xb)[i] = p;
    }
}

// =================== weight transposes (fp32 src -> bf16 transposed) ===================
// W1 (j,k,n) fp32 -> W1t (j,n,k) bf16, j=0..5 (3 gate then 3 msg)
__global__ void k_transpose_w1(const float* __restrict__ gw1,
                               const float* __restrict__ mw1,
                               unsigned short* __restrict__ W1t) {
    int idx = blockIdx.x * 256 + threadIdx.x;      // 6*65536
    int j = idx >> 16;
    int rem = idx & 65535;
    int n = rem >> 8, k = rem & 255;
    const float* src = (j < 3) ? (gw1 + (size_t)j * 65536)
                               : (mw1 + (size_t)(j - 3) * 65536);
    W1t[(size_t)idx] = f2bf(src[k * 256 + n]);
}
// mWo (h,k,f) fp32 -> Wo2t (h,f,k) bf16
__global__ void k_transpose_wo(const float* __restrict__ mwo,
                               unsigned short* __restrict__ Wot) {
    int idx = blockIdx.x * 256 + threadIdx.x;      // 3*32768
    int h = idx / 32768;
    int rem = idx % 32768;
    int f = rem >> 8, k = rem & 255;
    Wot[idx] = f2bf(mwo[(size_t)h * 32768 + k * 128 + f]);
}

// =================== CSR build ===================
__global__ void k_hist(const int* __restrict__ idx, int* __restrict__ cnt) {
    int e = blockIdx.x * 256 + threadIdx.x;
    if (e < MM) atomicAdd(&cnt[idx[e]], 1);
}
__global__ void k_scan1(const int* __restrict__ cnt, int* __restrict__ pincl, int* __restrict__ bsum) {
    __shared__ int s[256];
    int t = threadIdx.x;
    int i = blockIdx.x * 256 + t;
    int v = (i < NN) ? cnt[i] : 0;
    s[t] = v; __syncthreads();
    for (int o = 1; o < 256; o <<= 1) {
        int add = (t >= o) ? s[t - o] : 0;
        __syncthreads();
        s[t] += add;
        __syncthreads();
    }
    if (i < NN) pincl[i] = s[t];
    if (t == 255) bsum[blockIdx.x] = s[255];
}
__global__ void k_scan2(const int* __restrict__ bsum, int* __restrict__ boff, int nb) {
    __shared__ int s[512];
    int t = threadIdx.x;
    int v = (t < nb) ? bsum[t] : 0;
    s[t] = v; __syncthreads();
    for (int o = 1; o < 512; o <<= 1) {
        int add = (t >= o) ? s[t - o] : 0;
        __syncthreads();
        s[t] += add;
        __syncthreads();
    }
    if (t < nb) boff[t] = s[t] - v;
}
__global__ void k_scan3(const int* __restrict__ pincl, const int* __restrict__ boff, int* __restrict__ rp) {
    int i = blockIdx.x * 256 + threadIdx.x;
    if (i < NN) rp[i + 1] = pincl[i] + boff[i >> 8];
    if (i == 0) rp[0] = 0;
}
__global__ void k_scatter(const int* __restrict__ self, const int* __restrict__ rp,
                          int* __restrict__ fill, int* __restrict__ elist) {
    int e = blockIdx.x * 256 + threadIdx.x;
    if (e < MM) {
        int n = self[e];
        int pos = atomicAdd(&fill[n], 1);
        elist[rp[n] + pos] = e;
    }
}
__global__ void k_perm(const int* __restrict__ elist, const int* __restrict__ self,
                       const int* __restrict__ nbr, int* __restrict__ selfp, int* __restrict__ nbrp) {
    int i = blockIdx.x * 256 + threadIdx.x;
    if (i < MM) {
        int e = elist[i];
        selfp[i] = self[e];
        nbrp[i] = nbr[e];
    }
}

// =================== direct BN stats: GEMM1 pattern, no h1 store ===================
__global__ __launch_bounds__(256, 2)
void k_statsA(const unsigned short* __restrict__ x,
              const int* __restrict__ self_idx, const int* __restrict__ nbr_idx,
              const unsigned short* __restrict__ W1t,
              float* __restrict__ stats_s, float* __restrict__ stats_q) {
    __shared__ unsigned short As[128][72];
    __shared__ unsigned short Bs[128][72];
    __shared__ float sred[512];

    const int tid = threadIdx.x;
    sred[tid] = 0.f; sred[tid + 256] = 0.f;
    __syncthreads();

    const int lane = tid & 63, w = tid >> 6;
    const int lr = lane & 15, q = lane >> 4;
    const int r0 = tid >> 1, hf = tid & 1;

    float ssum[2][8], ssq[2][8];
#pragma unroll
    for (int a = 0; a < 2; a++)
#pragma unroll
        for (int b = 0; b < 8; b++) { ssum[a][b] = 0.f; ssq[a][b] = 0.f; }

    for (int t = blockIdx.x; t < NTILES; t += gridDim.x) {
        const int m0 = t * 128;
        for (int nh = 0; nh < 2; nh++) {
            floatx4 acc[2][8];
#pragma unroll
            for (int a = 0; a < 2; a++)
#pragma unroll
                for (int b = 0; b < 8; b++)
#pragma unroll
                    for (int r = 0; r < 4; r++) acc[a][b][r] = 0.f;

            for (int kc = 0; kc < 4; kc++) {
                {
                    int e = m0 + r0;
                    const int* pp = (kc < 2) ? self_idx : nbr_idx;
                    int node = (e < MM) ? pp[e] : 0;
                    const unsigned short* src = x + (size_t)node * FD + (kc & 1) * 64 + hf * 32;
#pragma unroll
                    for (int u = 0; u < 4; u++)
                        *(uint4*)&As[r0][hf * 32 + u * 8] = *(const uint4*)(src + u * 8);
                }
                {
                    const unsigned short* src = W1t + (size_t)(nh * 128 + r0) * KK + kc * 64 + hf * 32;
#pragma unroll
                    for (int u = 0; u < 4; u++)
                        *(uint4*)&Bs[r0][hf * 32 + u * 8] = *(const uint4*)(src + u * 8);
                }
                __syncthreads();
#pragma unroll
                for (int ks = 0; ks < 64; ks += 32) {
                    bf16x8 aF[2], bF[8];
#pragma unroll
                    for (int mi = 0; mi < 2; mi++)
                        aF[mi] = *(const bf16x8*)&As[w * 32 + mi * 16 + lr][ks + q * 8];
#pragma unroll
                    for (int nj = 0; nj < 8; nj++)
                        bF[nj] = *(const bf16x8*)&Bs[nj * 16 + lr][ks + q * 8];
#pragma unroll
                    for (int mi = 0; mi < 2; mi++)
#pragma unroll
                        for (int nj = 0; nj < 8; nj++)
                            acc[mi][nj] = __builtin_amdgcn_mfma_f32_16x16x32_bf16(aF[mi], bF[nj], acc[mi][nj], 0, 0, 0);
                }
                __syncthreads();
            }
#pragma unroll
            for (int mi = 0; mi < 2; mi++)
#pragma unroll
                for (int nj = 0; nj < 8; nj++)
#pragma unroll
                    for (int r = 0; r < 4; r++) {
                        int gr = m0 + w * 32 + mi * 16 + q * 4 + r;
                        if (gr < MM) {
                            float v = fin(acc[mi][nj][r]);
                            ssum[nh][nj] += v;
                            ssq[nh][nj] += v * v;
                        }
                    }
        }
    }
#pragma unroll
    for (int nh = 0; nh < 2; nh++)
#pragma unroll
        for (int nj = 0; nj < 8; nj++) {
            float v = ssum[nh][nj], v2 = ssq[nh][nj];
            v += __shfl_xor(v, 16);  v += __shfl_xor(v, 32);
            v2 += __shfl_xor(v2, 16); v2 += __shfl_xor(v2, 32);
            if (q == 0) {
                atomicAdd(&sred[nh * 128 + nj * 16 + lr], v);
                atomicAdd(&sred[256 + nh * 128 + nj * 16 + lr], v2);
            }
        }
    __syncthreads();
    atomicAdd(&stats_s[tid], sred[tid]);
    atomicAdd(&stats_q[tid], sred[tid + 256]);
}

// =================== finalize scale/shift per net ===================
__global__ void k_finalize6(const float* __restrict__ stats_s, const float* __restrict__ stats_q,
                            const float* __restrict__ gg, const float* __restrict__ gbe,
                            const float* __restrict__ mg, const float* __restrict__ mbe,
                            float* __restrict__ scaleA, float* __restrict__ shiftA) {
    int j = blockIdx.x;      // 0..5
    int c = threadIdx.x;     // 0..255
    const float* g    = (j < 3) ? gg + j * 256 : mg + (j - 3) * 256;
    const float* beta = (j < 3) ? gbe + j * 256 : mbe + (j - 3) * 256;
    float mu = fin(stats_s[j * 256 + c] / (float)MM);
    float var = fmaxf(fin(stats_q[j * 256 + c] / (float)MM - mu * mu), 0.f);
    float sc = fin(g[c] * rsqrtf(var + 1e-5f));
    scaleA[j * 256 + c] = sc;
    shiftA[j * 256 + c] = fin(beta[c] - mu * sc);
}

// =================== fused gate: GEMM1 + BN + SiLU + dot(Wo) ===================
__global__ __launch_bounds__(256, 2)
void k_gate(const unsigned short* __restrict__ x,
            const int* __restrict__ selfp, const int* __restrict__ nbrp,
            const unsigned short* __restrict__ W1t,
            const float* __restrict__ scale, const float* __restrict__ shift,
            const float* __restrict__ wo, const float* __restrict__ bo,
            float* __restrict__ glog) {
    __shared__ unsigned short As[128][72];
    __shared__ unsigned short Bs[128][72];
    __shared__ float sc[256], sh[256], wv[256];

    const int tid = threadIdx.x;
    const int m0 = blockIdx.x * 128;
    sc[tid] = scale[tid]; sh[tid] = shift[tid]; wv[tid] = wo[tid];
    __syncthreads();

    const int lane = tid & 63, w = tid >> 6;
    const int lr = lane & 15, q = lane >> 4;
    const int r0 = tid >> 1, hf = tid & 1;

    float dotp[2][4];
#pragma unroll
    for (int mi = 0; mi < 2; mi++)
#pragma unroll
        for (int r = 0; r < 4; r++) dotp[mi][r] = 0.f;

    for (int nh = 0; nh < 2; nh++) {
        floatx4 acc[2][8];
#pragma unroll
        for (int a = 0; a < 2; a++)
#pragma unroll
            for (int b = 0; b < 8; b++)
#pragma unroll
                for (int r = 0; r < 4; r++) acc[a][b][r] = 0.f;

        for (int kc = 0; kc < 4; kc++) {
            {
                int e = m0 + r0;
                const int* pp = (kc < 2) ? selfp : nbrp;
                int node = (e < MM) ? pp[e] : 0;
                const unsigned short* src = x + (size_t)node * FD + (kc & 1) * 64 + hf * 32;
#pragma unroll
                for (int u = 0; u < 4; u++)
                    *(uint4*)&As[r0][hf * 32 + u * 8] = *(const uint4*)(src + u * 8);
            }
            {
                const unsigned short* src = W1t + (size_t)(nh * 128 + r0) * KK + kc * 64 + hf * 32;
#pragma unroll
                for (int u = 0; u < 4; u++)
                    *(uint4*)&Bs[r0][hf * 32 + u * 8] = *(const uint4*)(src + u * 8);
            }
            __syncthreads();
#pragma unroll
            for (int ks = 0; ks < 64; ks += 32) {
                bf16x8 aF[2], bF[8];
#pragma unroll
                for (int mi = 0; mi < 2; mi++)
                    aF[mi] = *(const bf16x8*)&As[w * 32 + mi * 16 + lr][ks + q * 8];
#pragma unroll
                for (int nj = 0; nj < 8; nj++)
                    bF[nj] = *(const bf16x8*)&Bs[nj * 16 + lr][ks + q * 8];
#pragma unroll
                for (int mi = 0; mi < 2; mi++)
#pragma unroll
                    for (int nj = 0; nj < 8; nj++)
                        acc[mi][nj] = __builtin_amdgcn_mfma_f32_16x16x32_bf16(aF[mi], bF[nj], acc[mi][nj], 0, 0, 0);
            }
            __syncthreads();
        }
#pragma unroll
        for (int mi = 0; mi < 2; mi++)
#pragma unroll
            for (int r = 0; r < 4; r++) {
                float d = 0.f;
#pragma unroll
                for (int nj = 0; nj < 8; nj++) {
                    int cg = nh * 128 + nj * 16 + lr;
                    float v = acc[mi][nj][r] * sc[cg] + sh[cg];
                    d += silu(v) * wv[cg];
                }
                dotp[mi][r] += d;
            }
    }
    float b0 = bo[0];
#pragma unroll
    for (int mi = 0; mi < 2; mi++)
#pragma unroll
        for (int r = 0; r < 4; r++) {
            float v = dotp[mi][r];
            v += __shfl_xor(v, 1); v += __shfl_xor(v, 2);
            v += __shfl_xor(v, 4); v += __shfl_xor(v, 8);
            if (lr == 0) {
                int row = w * 32 + mi * 16 + q * 4 + r;
                int e = m0 + row;
                if (e < MM) glog[e] = fin(v + b0);
            }
        }
}

// =================== softmax coefficients per node ===================
__global__ void k_coef(const int* __restrict__ rp, const float* __restrict__ glog,
                       float* __restrict__ coef, const float* __restrict__ ew,
                       const int* __restrict__ nbrp, const float* __restrict__ powp) {
    int n = blockIdx.x * 256 + threadIdx.x;
    if (n >= NN) return;
    int b = rp[n], e = rp[n + 1];
    if (e <= b) return;
    for (int h = 0; h < NHEADS; h++) {
        const float* gl = glog + (size_t)h * MM;
        float* cf = coef + (size_t)h * MM;
        float p = powp[h];
        float gmax = -3.4e38f;
        for (int i = b; i < e; i++) gmax = fmaxf(gmax, gl[i]);
        float den = 0.f;
        for (int i = b; i < e; i++) {
            float wv = ew[nbrp[i]];
            float u = fin(powf(wv, p) * __expf(gl[i] - gmax));
            cf[i] = u; den += u;
        }
        float inv = fin(1.f / (den + 1e-10f));
        for (int i = b; i < e; i++) cf[i] = fin(cf[i] * inv);
    }
}

// =================== fused msg: GEMM1+BN+SiLU+GEMM2, coef-weighted seg-reduce ==========
__global__ __launch_bounds__(256, 2)
void k_msg(const unsigned short* __restrict__ x,
           const int* __restrict__ selfp, const int* __restrict__ nbrp,
           const unsigned short* __restrict__ W1t,
           const float* __restrict__ scale, const float* __restrict__ shift,
           const unsigned short* __restrict__ Wo2t,      // [128 f][256 k]
           const float* __restrict__ bo2,                // [128]
           const float* __restrict__ coef,               // perm order, this head
           const int* __restrict__ rp,
           float* __restrict__ out_acc) {
    __shared__ unsigned short As[128][72];
    __shared__ unsigned short Bs[128][72];
    __shared__ unsigned short ActC[128][72];   // reused as float[128][33] in epilogue
    __shared__ float sc[256], sh[256];
    __shared__ float bvec[128], cf[128];
    __shared__ int nid[128];

    const int tid = threadIdx.x;
    const int m0 = blockIdx.x * 128;
    sc[tid] = scale[tid]; sh[tid] = shift[tid];
    if (tid < 128) {
        bvec[tid] = bo2[tid];
        int e = m0 + tid;
        cf[tid] = (e < MM) ? fin(coef[e]) : 0.f;
        nid[tid] = (e < MM) ? selfp[e] : -1;
    }
    __syncthreads();

    const int lane = tid & 63, w = tid >> 6;
    const int lr = lane & 15, q = lane >> 4;
    const int r0 = tid >> 1, hf = tid & 1;

    floatx4 acc2[2][8];
#pragma unroll
    for (int a = 0; a < 2; a++)
#pragma unroll
        for (int b = 0; b < 8; b++)
#pragma unroll
            for (int r = 0; r < 4; r++) acc2[a][b][r] = 0.f;

    for (int nh = 0; nh < 2; nh++) {
        floatx4 acc[2][8];
#pragma unroll
        for (int a = 0; a < 2; a++)
#pragma unroll
            for (int b = 0; b < 8; b++)
#pragma unroll
                for (int r = 0; r < 4; r++) acc[a][b][r] = 0.f;

        for (int kc = 0; kc < 4; kc++) {
            {
                int e = m0 + r0;
                const int* pp = (kc < 2) ? selfp : nbrp;
                int node = (e < MM) ? pp[e] : 0;
                const unsigned short* src = x + (size_t)node * FD + (kc & 1) * 64 + hf * 32;
#pragma unroll
                for (int u = 0; u < 4; u++)
                    *(uint4*)&As[r0][hf * 32 + u * 8] = *(const uint4*)(src + u * 8);
            }
            {
                const unsigned short* src = W1t + (size_t)(nh * 128 + r0) * KK + kc * 64 + hf * 32;
#pragma unroll
                for (int u = 0; u < 4; u++)
                    *(uint4*)&Bs[r0][hf * 32 + u * 8] = *(const uint4*)(src + u * 8);
            }
            __syncthreads();
#pragma unroll
            for (int ks = 0; ks < 64; ks += 32) {
                bf16x8 aF[2], bF[8];
#pragma unroll
                for (int mi = 0; mi < 2; mi++)
                    aF[mi] = *(const bf16x8*)&As[w * 32 + mi * 16 + lr][ks + q * 8];
#pragma unroll
                for (int nj = 0; nj < 8; nj++)
                    bF[nj] = *(const bf16x8*)&Bs[nj * 16 + lr][ks + q * 8];
#pragma unroll
                for (int mi = 0; mi < 2; mi++)
#pragma unroll
                    for (int nj = 0; nj < 8; nj++)
                        acc[mi][nj] = __builtin_amdgcn_mfma_f32_16x16x32_bf16(aF[mi], bF[nj], acc[mi][nj], 0, 0, 0);
            }
            __syncthreads();
        }
        for (int kc2 = 0; kc2 < 2; kc2++) {
#pragma unroll
            for (int mi = 0; mi < 2; mi++)
#pragma unroll
                for (int njl = 0; njl < 4; njl++)
#pragma unroll
                    for (int r = 0; r < 4; r++) {
                        int nj = kc2 * 4 + njl;
                        int row = w * 32 + mi * 16 + q * 4 + r;
                        int cg = nh * 128 + nj * 16 + lr;
                        float v = acc[mi][nj][r] * sc[cg] + sh[cg];
                        ActC[row][njl * 16 + lr] = f2bf(fin(silu(v)));
                    }
            {
                const unsigned short* src = Wo2t + (size_t)r0 * KK + nh * 128 + kc2 * 64 + hf * 32;
#pragma unroll
                for (int u = 0; u < 4; u++)
                    *(uint4*)&Bs[r0][hf * 32 + u * 8] = *(const uint4*)(src + u * 8);
            }
            __syncthreads();
#pragma unroll
            for (int ks = 0; ks < 64; ks += 32) {
                bf16x8 aF[2], bF[8];
#pragma unroll
                for (int mi = 0; mi < 2; mi++)
                    aF[mi] = *(const bf16x8*)&ActC[w * 32 + mi * 16 + lr][ks + q * 8];
#pragma unroll
                for (int nj = 0; nj < 8; nj++)
                    bF[nj] = *(const bf16x8*)&Bs[nj * 16 + lr][ks + q * 8];
#pragma unroll
                for (int mi = 0; mi < 2; mi++)
#pragma unroll
                    for (int nj = 0; nj < 8; nj++)
                        acc2[mi][nj] = __builtin_amdgcn_mfma_f32_16x16x32_bf16(aF[mi], bF[nj], acc2[mi][nj], 0, 0, 0);
            }
            __syncthreads();
        }
    }
    auto W32 = (float (*)[33])(&ActC[0][0]);
    for (int pass = 0; pass < 4; pass++) {
#pragma unroll
        for (int mi = 0; mi < 2; mi++)
#pragma unroll
            for (int njl = 0; njl < 2; njl++)
#pragma unroll
                for (int r = 0; r < 4; r++) {
                    int nj = pass * 2 + njl;
                    int row = w * 32 + mi * 16 + q * 4 + r;
                    int col = nj * 16 + lr;
                    float v = acc2[mi][nj][r] + bvec[col];
                    W32[row][njl * 16 + lr] = fin(cf[row] * v);
                }
        __syncthreads();
        if (tid < 32) {
            int col = pass * 32 + tid;
            int cur = nid[0];
            float s = 0.f;
            for (int rr = 0; rr < 128; rr++) {
                int n2 = nid[rr];
                if (n2 != cur) {
                    if (cur >= 0) {
                        int rb = rp[cur], re = rp[cur + 1];
                        float* addr = out_acc + (size_t)cur * FD + col;
                        if (rb >= m0 && re <= m0 + 128) *addr += s;
                        else atomicAdd(addr, s);
                    }
                    cur = n2; s = 0.f;
                }
                s += W32[rr][tid];
            }
            if (cur >= 0) {
                int rb = rp[cur], re = rp[cur + 1];
                float* addr = out_acc + (size_t)cur * FD + col;
                if (rb >= m0 && re <= m0 + 128) *addr += s;
                else atomicAdd(addr, s);
            }
        }
        __syncthreads();
    }
}

// =================== final (in place): out = out/3 + x ===================
__global__ void k_finalout(float* __restrict__ out, const float* __restrict__ x) {
    int i = blockIdx.x * 256 + threadIdx.x;
    if (i < NN * FD) out[i] = fin(out[i]) * (1.f / 3.f) + x[i];
}

extern "C" void kernel_launch(void* const* d_in, const int* in_sizes, int n_in,
                              void* d_out, int out_size, void* d_ws, size_t ws_size,
                              hipStream_t stream) {
    const float* ew   = (const float*)d_in[0];
    const float* x    = (const float*)d_in[1];
    const float* gW1  = (const float*)d_in[2];
    const float* gg   = (const float*)d_in[4];
    const float* gbe  = (const float*)d_in[5];
    const float* gWo  = (const float*)d_in[6];
    const float* gbo  = (const float*)d_in[7];
    const float* mW1  = (const float*)d_in[8];
    const float* mg   = (const float*)d_in[10];
    const float* mbe  = (const float*)d_in[11];
    const float* mWo  = (const float*)d_in[12];
    const float* mbo  = (const float*)d_in[13];
    const float* powp = (const float*)d_in[14];
    const int* self_idx = (const int*)d_in[15];
    const int* nbr_idx  = (const int*)d_in[16];
    float* out = (float*)d_out;

    char* ws = (char*)d_ws;
    size_t off = 0;
    auto alloc = [&](size_t bytes) -> void* {
        size_t o = off;
        off += (bytes + 255) & ~(size_t)255;
        return (void*)(ws + o);
    };

    // ---- zero span (contiguous) ----
    float* stats_s = (float*)alloc(6ull * 256 * 4);
    float* stats_q = (float*)alloc(6ull * 256 * 4);
    int*   cnt     = (int*)alloc((size_t)NN * 4);
    int*   fill    = (int*)alloc((size_t)NN * 4);
    size_t zero_end = off;
    // ---- rest ----
    unsigned short* xb   = (unsigned short*)alloc((size_t)NN * FD * 2);
    unsigned short* W1t  = (unsigned short*)alloc(6ull * 65536 * 2);
    unsigned short* Wo2t = (unsigned short*)alloc(3ull * 32768 * 2);
    float* scaleA = (float*)alloc(6ull * 256 * 4);
    float* shiftA = (float*)alloc(6ull * 256 * 4);
    int*   rp     = (int*)alloc((size_t)(NN + 1) * 4);
    int*   pincl  = (int*)alloc((size_t)NN * 4);
    int*   bsum   = (int*)alloc(512 * 4);
    int*   boff   = (int*)alloc(512 * 4);
    int*   elist  = (int*)alloc((size_t)MM * 4);
    int*   selfp  = (int*)alloc((size_t)MM * 4);
    int*   nbrp   = (int*)alloc((size_t)MM * 4);
    float* glog   = (float*)alloc(3ull * MM * 4);
    float* coef   = (float*)alloc(3ull * MM * 4);
    if (off > ws_size) return;   // ~46 MB needed

    int zwords = (int)(zero_end / 4);
    k_zero<<<(zwords + 255) / 256, 256, 0, stream>>>(stats_s, zwords);
    k_zero<<<(NN * FD + 255) / 256, 256, 0, stream>>>(out, NN * FD);  // out doubles as accumulator

    k_castx<<<(NN * FD / 2 + 255) / 256, 256, 0, stream>>>(x, xb);
    k_transpose_w1<<<1536, 256, 0, stream>>>(gW1, mW1, W1t);
    k_transpose_wo<<<384, 256, 0, stream>>>(mWo, Wo2t);

    k_hist<<<1954, 256, 0, stream>>>(self_idx, cnt);
    int nb1 = (NN + 255) / 256;   // 391
    k_scan1<<<nb1, 256, 0, stream>>>(cnt, pincl, bsum);
    k_scan2<<<1, 512, 0, stream>>>(bsum, boff, nb1);
    k_scan3<<<nb1, 256, 0, stream>>>(pincl, boff, rp);
    k_scatter<<<1954, 256, 0, stream>>>(self_idx, rp, fill, elist);
    k_perm<<<1954, 256, 0, stream>>>(elist, self_idx, nbr_idx, selfp, nbrp);

    for (int j = 0; j < 6; j++)
        k_statsA<<<1024, 256, 0, stream>>>(xb, self_idx, nbr_idx,
                                           W1t + (size_t)j * 65536,
                                           stats_s + j * 256, stats_q + j * 256);
    k_finalize6<<<6, 256, 0, stream>>>(stats_s, stats_q, gg, gbe, mg, mbe, scaleA, shiftA);

    for (int h = 0; h < 3; h++)
        k_gate<<<NTILES, 256, 0, stream>>>(xb, selfp, nbrp, W1t + (size_t)h * 65536,
                                           scaleA + h * 256, shiftA + h * 256,
                                           gWo + h * 256, gbo + h, glog + (size_t)h * MM);
    k_coef<<<nb1, 256, 0, stream>>>(rp, glog, coef, ew, nbrp, powp);
    for (int h = 0; h < 3; h++) {
        int j = 3 + h;
        k_msg<<<NTILES, 256, 0, stream>>>(xb, selfp, nbrp, W1t + (size_t)j * 65536,
                                          scaleA + j * 256, shiftA + j * 256,
                                          Wo2t + (size_t)h * 32768, mbo + h * 128,
                                          coef + (size_t)h * MM, rp, out);
    }
    k_finalout<<<(NN * FD + 255) / 256, 256, 0, stream>>>(out, x);
}

// Round 7
// 2021.510 us; speedup vs baseline: 2.0555x; 2.0555x over previous
//
#include <hip/hip_runtime.h>
#include <stdint.h>

#define NN 100000
#define MM 500000
#define FD 128
#define KK 256
#define NHEADS 3
#define NTILES 3907

typedef __attribute__((ext_vector_type(8))) __bf16 bf16x8;
typedef __attribute__((ext_vector_type(4))) float floatx4;

__device__ __forceinline__ float bf2f(unsigned short u) {
    union { uint32_t i; float f; } c; c.i = ((uint32_t)u) << 16; return c.f;
}
__device__ __forceinline__ unsigned short f2bf(float f) {
    union { float f; uint32_t i; } c; c.f = f;
    uint32_t i = c.i;
    return (unsigned short)((i + 0x7FFFu + ((i >> 16) & 1u)) >> 16);
}
__device__ __forceinline__ float silu(float a) { return a / (1.f + __expf(-a)); }
__device__ __forceinline__ float fin(float v) {
    return (v == v && fabsf(v) < 1e30f) ? v : 0.f;
}

// =================== zero ===================
__global__ void k_zero(float* __restrict__ p, int nwords) {
    int i = blockIdx.x * 256 + threadIdx.x;
    if (i < nwords) p[i] = 0.f;
}

// =================== cast x (fp32) -> xb (bf16) ===================
__global__ void k_castx(const float* __restrict__ x, unsigned short* __restrict__ xb) {
    int i = blockIdx.x * 256 + threadIdx.x;   // pair index
    if (i < NN * FD / 2) {
        float2 v = ((const float2*)x)[i];
        uint32_t p = (uint32_t)f2bf(v.x) | ((uint32_t)f2bf(v.y) << 16);
        ((uint32_t*)xb)[i] = p;
    }
}

// =================== weight transposes (fp32 src -> bf16 transposed) ===================
__global__ void k_transpose_w1(const float* __restrict__ gw1,
                               const float* __restrict__ mw1,
                               unsigned short* __restrict__ W1t) {
    int idx = blockIdx.x * 256 + threadIdx.x;      // 6*65536
    int j = idx >> 16;
    int rem = idx & 65535;
    int n = rem >> 8, k = rem & 255;
    const float* src = (j < 3) ? (gw1 + (size_t)j * 65536)
                               : (mw1 + (size_t)(j - 3) * 65536);
    W1t[(size_t)idx] = f2bf(src[k * 256 + n]);
}
__global__ void k_transpose_wo(const float* __restrict__ mwo,
                               unsigned short* __restrict__ Wot) {
    int idx = blockIdx.x * 256 + threadIdx.x;      // 3*32768
    int h = idx / 32768;
    int rem = idx % 32768;
    int f = rem >> 8, k = rem & 255;
    Wot[idx] = f2bf(mwo[(size_t)h * 32768 + k * 128 + f]);
}

// =================== CSR build ===================
__global__ void k_hist(const int* __restrict__ idx, int* __restrict__ cnt) {
    int e = blockIdx.x * 256 + threadIdx.x;
    if (e < MM) atomicAdd(&cnt[idx[e]], 1);
}
__global__ void k_scan1(const int* __restrict__ cnt, int* __restrict__ pincl, int* __restrict__ bsum) {
    __shared__ int s[256];
    int t = threadIdx.x;
    int i = blockIdx.x * 256 + t;
    int v = (i < NN) ? cnt[i] : 0;
    s[t] = v; __syncthreads();
    for (int o = 1; o < 256; o <<= 1) {
        int add = (t >= o) ? s[t - o] : 0;
        __syncthreads();
        s[t] += add;
        __syncthreads();
    }
    if (i < NN) pincl[i] = s[t];
    if (t == 255) bsum[blockIdx.x] = s[255];
}
__global__ void k_scan2(const int* __restrict__ bsum, int* __restrict__ boff, int nb) {
    __shared__ int s[512];
    int t = threadIdx.x;
    int v = (t < nb) ? bsum[t] : 0;
    s[t] = v; __syncthreads();
    for (int o = 1; o < 512; o <<= 1) {
        int add = (t >= o) ? s[t - o] : 0;
        __syncthreads();
        s[t] += add;
        __syncthreads();
    }
    if (t < nb) boff[t] = s[t] - v;
}
__global__ void k_scan3(const int* __restrict__ pincl, const int* __restrict__ boff, int* __restrict__ rp) {
    int i = blockIdx.x * 256 + threadIdx.x;
    if (i < NN) rp[i + 1] = pincl[i] + boff[i >> 8];
    if (i == 0) rp[0] = 0;
}
__global__ void k_scatter(const int* __restrict__ self, const int* __restrict__ rp,
                          int* __restrict__ fill, int* __restrict__ elist) {
    int e = blockIdx.x * 256 + threadIdx.x;
    if (e < MM) {
        int n = self[e];
        int pos = atomicAdd(&fill[n], 1);
        elist[rp[n] + pos] = e;
    }
}
__global__ void k_perm(const int* __restrict__ elist, const int* __restrict__ self,
                       const int* __restrict__ nbr, int* __restrict__ selfp, int* __restrict__ nbrp) {
    int i = blockIdx.x * 256 + threadIdx.x;
    if (i < MM) {
        int e = elist[i];
        selfp[i] = self[e];
        nbrp[i] = nbr[e];
    }
}

// =================== colsum of fea (count-weighted node sums, fp32 x) ===================
__global__ void k_colsum(const float* __restrict__ x,
                         const int* __restrict__ cnt_self, const int* __restrict__ cnt_nbr,
                         float* __restrict__ colsum) {
    int t = threadIdx.x;
    int col = t & 127, part = t >> 7;
    const int* cp = part ? cnt_nbr : cnt_self;
    int n0 = blockIdx.x * 512;
    float a = 0.f;
    for (int i = 0; i < 512; i++) {
        int n = n0 + i;
        if (n < NN) {
            float c = (float)cp[n];
            a += c * x[(size_t)n * FD + col];
        }
    }
    atomicAdd(&colsum[part * 128 + col], a);
}

// =================== S = fea^T fea (Gram over edges, transposed LDS staging) ==========
#define NCH 7813
#define CPB 62
__global__ __launch_bounds__(256, 2)
void k_S(const unsigned short* __restrict__ xb,
         const int* __restrict__ self_idx, const int* __restrict__ nbr_idx,
         float* __restrict__ S) {
    __shared__ unsigned short LT[256][72];   // [feat][edge 64 + pad8]
    const int tid = threadIdx.x;
    const int e_l = tid & 63;       // edge within chunk
    const int half = tid >> 6;      // feat group: half*64 .. +64
    const int ti = blockIdx.y >> 1, tj = blockIdx.y & 1;
    const int lane = tid & 63, w = tid >> 6;
    const int lr = lane & 15, q = lane >> 4;

    int cbeg = blockIdx.x * CPB;
    int cend = cbeg + CPB; if (cend > NCH) cend = NCH;

    floatx4 acc[2][8];
#pragma unroll
    for (int a = 0; a < 2; a++)
#pragma unroll
        for (int b = 0; b < 8; b++)
#pragma unroll
            for (int r = 0; r < 4; r++) acc[a][b][r] = 0.f;

    for (int ch = cbeg; ch < cend; ch++) {
        int e = ch * 64 + e_l;
        union { uint4 v[8]; unsigned short us[64]; } buf;
        if (e < MM) {
            int node = (half < 2) ? self_idx[e] : nbr_idx[e];
            const unsigned short* src = xb + (size_t)node * FD + (half & 1) * 64;
#pragma unroll
            for (int u2 = 0; u2 < 8; u2++) buf.v[u2] = *(const uint4*)(src + u2 * 8);
        } else {
#pragma unroll
            for (int u2 = 0; u2 < 8; u2++) { buf.v[u2].x = 0u; buf.v[u2].y = 0u; buf.v[u2].z = 0u; buf.v[u2].w = 0u; }
        }
        __syncthreads();   // prev MFMA reads done before overwrite
#pragma unroll
        for (int j2 = 0; j2 < 64; j2++)
            LT[half * 64 + j2][e_l] = buf.us[j2];
        __syncthreads();
#pragma unroll
        for (int ks = 0; ks < 64; ks += 32) {
            bf16x8 aF[2], bF[8];
#pragma unroll
            for (int mi = 0; mi < 2; mi++)
                aF[mi] = *(const bf16x8*)&LT[ti * 128 + w * 32 + mi * 16 + lr][ks + q * 8];
#pragma unroll
            for (int nj = 0; nj < 8; nj++)
                bF[nj] = *(const bf16x8*)&LT[tj * 128 + nj * 16 + lr][ks + q * 8];
#pragma unroll
            for (int mi = 0; mi < 2; mi++)
#pragma unroll
                for (int nj = 0; nj < 8; nj++)
                    acc[mi][nj] = __builtin_amdgcn_mfma_f32_16x16x32_bf16(aF[mi], bF[nj], acc[mi][nj], 0, 0, 0);
        }
    }
#pragma unroll
    for (int mi = 0; mi < 2; mi++)
#pragma unroll
        for (int nj = 0; nj < 8; nj++)
#pragma unroll
            for (int r = 0; r < 4; r++) {
                int row = ti * 128 + w * 32 + mi * 16 + q * 4 + r;
                int col = tj * 128 + nj * 16 + lr;
                atomicAdd(&S[row * 256 + col], acc[mi][nj][r]);
            }
}

// =================== per-net BN scale/shift from S + colsum ===================
__global__ void k_stats(const float* __restrict__ S, const float* __restrict__ colsum,
                        const unsigned short* __restrict__ W1t,
                        const float* __restrict__ gg, const float* __restrict__ gbe,
                        const float* __restrict__ mg, const float* __restrict__ mbe,
                        float* __restrict__ scaleA, float* __restrict__ shiftA) {
    __shared__ float ws[16][257];
    __shared__ float qq[16], uu[16];
    int t = threadIdx.x;
    int j = blockIdx.y;
    int c0 = blockIdx.x * 16;
    const unsigned short* Wn = W1t + (size_t)j * 65536;
    const float* g    = (j < 3) ? gg + j * 256 : mg + (j - 3) * 256;
    const float* beta = (j < 3) ? gbe + j * 256 : mbe + (j - 3) * 256;
#pragma unroll
    for (int i = 0; i < 16; i++) ws[i][t] = bf2f(Wn[(size_t)(c0 + i) * 256 + t]);
    if (t < 16) { qq[t] = 0.f; uu[t] = 0.f; }
    __syncthreads();
    float vpart[16];
#pragma unroll
    for (int i = 0; i < 16; i++) vpart[i] = 0.f;
    for (int k = 0; k < 256; k++) {
        float s = S[k * 256 + t];          // S symmetric: column read = (S w)_t
#pragma unroll
        for (int i = 0; i < 16; i++) vpart[i] += s * ws[i][k];
    }
    float cs = colsum[t];
    int lane = t & 63;
#pragma unroll
    for (int i = 0; i < 16; i++) {
        float q1 = ws[i][t] * vpart[i];
        float u1 = cs * ws[i][t];
#pragma unroll
        for (int m = 1; m <= 32; m <<= 1) { q1 += __shfl_xor(q1, m); u1 += __shfl_xor(u1, m); }
        if (lane == 0) { atomicAdd(&qq[i], q1); atomicAdd(&uu[i], u1); }
    }
    __syncthreads();
    if (t < 16) {
        int c = c0 + t;
        float mu = fin(uu[t] / (float)MM);
        float var = fmaxf(fin(qq[t] / (float)MM - mu * mu), 0.f);
        float sc = fin(g[c] * rsqrtf(var + 1e-5f));
        scaleA[j * 256 + c] = sc;
        shiftA[j * 256 + c] = fin(beta[c] - mu * sc);
    }
}

// =================== fused gate: GEMM1 + BN + SiLU + dot(Wo) ===================
__global__ __launch_bounds__(256, 2)
void k_gate(const unsigned short* __restrict__ x,
            const int* __restrict__ selfp, const int* __restrict__ nbrp,
            const unsigned short* __restrict__ W1t,
            const float* __restrict__ scale, const float* __restrict__ shift,
            const float* __restrict__ wo, const float* __restrict__ bo,
            float* __restrict__ glog) {
    __shared__ unsigned short As[128][72];
    __shared__ unsigned short Bs[128][72];
    __shared__ float sc[256], sh[256], wv[256];

    const int tid = threadIdx.x;
    const int m0 = blockIdx.x * 128;
    sc[tid] = scale[tid]; sh[tid] = shift[tid]; wv[tid] = wo[tid];
    __syncthreads();

    const int lane = tid & 63, w = tid >> 6;
    const int lr = lane & 15, q = lane >> 4;
    const int r0 = tid >> 1, hf = tid & 1;

    float dotp[2][4];
#pragma unroll
    for (int mi = 0; mi < 2; mi++)
#pragma unroll
        for (int r = 0; r < 4; r++) dotp[mi][r] = 0.f;

    for (int nh = 0; nh < 2; nh++) {
        floatx4 acc[2][8];
#pragma unroll
        for (int a = 0; a < 2; a++)
#pragma unroll
            for (int b = 0; b < 8; b++)
#pragma unroll
                for (int r = 0; r < 4; r++) acc[a][b][r] = 0.f;

        for (int kc = 0; kc < 4; kc++) {
            {
                int e = m0 + r0;
                const int* pp = (kc < 2) ? selfp : nbrp;
                int node = (e < MM) ? pp[e] : 0;
                const unsigned short* src = x + (size_t)node * FD + (kc & 1) * 64 + hf * 32;
#pragma unroll
                for (int u = 0; u < 4; u++)
                    *(uint4*)&As[r0][hf * 32 + u * 8] = *(const uint4*)(src + u * 8);
            }
            {
                const unsigned short* src = W1t + (size_t)(nh * 128 + r0) * KK + kc * 64 + hf * 32;
#pragma unroll
                for (int u = 0; u < 4; u++)
                    *(uint4*)&Bs[r0][hf * 32 + u * 8] = *(const uint4*)(src + u * 8);
            }
            __syncthreads();
#pragma unroll
            for (int ks = 0; ks < 64; ks += 32) {
                bf16x8 aF[2], bF[8];
#pragma unroll
                for (int mi = 0; mi < 2; mi++)
                    aF[mi] = *(const bf16x8*)&As[w * 32 + mi * 16 + lr][ks + q * 8];
#pragma unroll
                for (int nj = 0; nj < 8; nj++)
                    bF[nj] = *(const bf16x8*)&Bs[nj * 16 + lr][ks + q * 8];
#pragma unroll
                for (int mi = 0; mi < 2; mi++)
#pragma unroll
                    for (int nj = 0; nj < 8; nj++)
                        acc[mi][nj] = __builtin_amdgcn_mfma_f32_16x16x32_bf16(aF[mi], bF[nj], acc[mi][nj], 0, 0, 0);
            }
            __syncthreads();
        }
#pragma unroll
        for (int mi = 0; mi < 2; mi++)
#pragma unroll
            for (int r = 0; r < 4; r++) {
                float d = 0.f;
#pragma unroll
                for (int nj = 0; nj < 8; nj++) {
                    int cg = nh * 128 + nj * 16 + lr;
                    float v = acc[mi][nj][r] * sc[cg] + sh[cg];
                    d += silu(v) * wv[cg];
                }
                dotp[mi][r] += d;
            }
    }
    float b0 = bo[0];
#pragma unroll
    for (int mi = 0; mi < 2; mi++)
#pragma unroll
        for (int r = 0; r < 4; r++) {
            float v = dotp[mi][r];
            v += __shfl_xor(v, 1); v += __shfl_xor(v, 2);
            v += __shfl_xor(v, 4); v += __shfl_xor(v, 8);
            if (lr == 0) {
                int row = w * 32 + mi * 16 + q * 4 + r;
                int e = m0 + row;
                if (e < MM) glog[e] = fin(v + b0);
            }
        }
}

// =================== softmax coefficients per node ===================
__global__ void k_coef(const int* __restrict__ rp, const float* __restrict__ glog,
                       float* __restrict__ coef, const float* __restrict__ ew,
                       const int* __restrict__ nbrp, const float* __restrict__ powp) {
    int n = blockIdx.x * 256 + threadIdx.x;
    if (n >= NN) return;
    int b = rp[n], e = rp[n + 1];
    if (e <= b) return;
    for (int h = 0; h < NHEADS; h++) {
        const float* gl = glog + (size_t)h * MM;
        float* cf = coef + (size_t)h * MM;
        float p = powp[h];
        float gmax = -3.4e38f;
        for (int i = b; i < e; i++) gmax = fmaxf(gmax, gl[i]);
        float den = 0.f;
        for (int i = b; i < e; i++) {
            float wv = ew[nbrp[i]];
            float u = fin(powf(wv, p) * __expf(gl[i] - gmax));
            cf[i] = u; den += u;
        }
        float inv = fin(1.f / (den + 1e-10f));
        for (int i = b; i < e; i++) cf[i] = fin(cf[i] * inv);
    }
}

// =================== fused msg: GEMM1+BN+SiLU+GEMM2, atomic scatter epilogue ==========
__global__ __launch_bounds__(256, 2)
void k_msg(const unsigned short* __restrict__ x,
           const int* __restrict__ selfp, const int* __restrict__ nbrp,
           const unsigned short* __restrict__ W1t,
           const float* __restrict__ scale, const float* __restrict__ shift,
           const unsigned short* __restrict__ Wo2t,      // [128 f][256 k]
           const float* __restrict__ bo2,                // [128]
           const float* __restrict__ coef,               // perm order, this head
           float* __restrict__ out_acc) {
    __shared__ unsigned short As[128][72];
    __shared__ unsigned short Bs[128][72];
    __shared__ unsigned short ActC[128][72];
    __shared__ float sc[256], sh[256];
    __shared__ float bvec[128], cf[128];
    __shared__ int nid[128];

    const int tid = threadIdx.x;
    const int m0 = blockIdx.x * 128;
    sc[tid] = scale[tid]; sh[tid] = shift[tid];
    if (tid < 128) {
        bvec[tid] = bo2[tid];
        int e = m0 + tid;
        cf[tid] = (e < MM) ? fin(coef[e]) : 0.f;
        nid[tid] = (e < MM) ? selfp[e] : -1;
    }
    __syncthreads();

    const int lane = tid & 63, w = tid >> 6;
    const int lr = lane & 15, q = lane >> 4;
    const int r0 = tid >> 1, hf = tid & 1;

    floatx4 acc2[2][8];
#pragma unroll
    for (int a = 0; a < 2; a++)
#pragma unroll
        for (int b = 0; b < 8; b++)
#pragma unroll
            for (int r = 0; r < 4; r++) acc2[a][b][r] = 0.f;

    for (int nh = 0; nh < 2; nh++) {
        floatx4 acc[2][8];
#pragma unroll
        for (int a = 0; a < 2; a++)
#pragma unroll
            for (int b = 0; b < 8; b++)
#pragma unroll
                for (int r = 0; r < 4; r++) acc[a][b][r] = 0.f;

        for (int kc = 0; kc < 4; kc++) {
            {
                int e = m0 + r0;
                const int* pp = (kc < 2) ? selfp : nbrp;
                int node = (e < MM) ? pp[e] : 0;
                const unsigned short* src = x + (size_t)node * FD + (kc & 1) * 64 + hf * 32;
#pragma unroll
                for (int u = 0; u < 4; u++)
                    *(uint4*)&As[r0][hf * 32 + u * 8] = *(const uint4*)(src + u * 8);
            }
            {
                const unsigned short* src = W1t + (size_t)(nh * 128 + r0) * KK + kc * 64 + hf * 32;
#pragma unroll
                for (int u = 0; u < 4; u++)
                    *(uint4*)&Bs[r0][hf * 32 + u * 8] = *(const uint4*)(src + u * 8);
            }
            __syncthreads();
#pragma unroll
            for (int ks = 0; ks < 64; ks += 32) {
                bf16x8 aF[2], bF[8];
#pragma unroll
                for (int mi = 0; mi < 2; mi++)
                    aF[mi] = *(const bf16x8*)&As[w * 32 + mi * 16 + lr][ks + q * 8];
#pragma unroll
                for (int nj = 0; nj < 8; nj++)
                    bF[nj] = *(const bf16x8*)&Bs[nj * 16 + lr][ks + q * 8];
#pragma unroll
                for (int mi = 0; mi < 2; mi++)
#pragma unroll
                    for (int nj = 0; nj < 8; nj++)
                        acc[mi][nj] = __builtin_amdgcn_mfma_f32_16x16x32_bf16(aF[mi], bF[nj], acc[mi][nj], 0, 0, 0);
            }
            __syncthreads();
        }
        for (int kc2 = 0; kc2 < 2; kc2++) {
#pragma unroll
            for (int mi = 0; mi < 2; mi++)
#pragma unroll
                for (int njl = 0; njl < 4; njl++)
#pragma unroll
                    for (int r = 0; r < 4; r++) {
                        int nj = kc2 * 4 + njl;
                        int row = w * 32 + mi * 16 + q * 4 + r;
                        int cg = nh * 128 + nj * 16 + lr;
                        float v = acc[mi][nj][r] * sc[cg] + sh[cg];
                        ActC[row][njl * 16 + lr] = f2bf(fin(silu(v)));
                    }
            {
                const unsigned short* src = Wo2t + (size_t)r0 * KK + nh * 128 + kc2 * 64 + hf * 32;
#pragma unroll
                for (int u = 0; u < 4; u++)
                    *(uint4*)&Bs[r0][hf * 32 + u * 8] = *(const uint4*)(src + u * 8);
            }
            __syncthreads();
#pragma unroll
            for (int ks = 0; ks < 64; ks += 32) {
                bf16x8 aF[2], bF[8];
#pragma unroll
                for (int mi = 0; mi < 2; mi++)
                    aF[mi] = *(const bf16x8*)&ActC[w * 32 + mi * 16 + lr][ks + q * 8];
#pragma unroll
                for (int nj = 0; nj < 8; nj++)
                    bF[nj] = *(const bf16x8*)&Bs[nj * 16 + lr][ks + q * 8];
#pragma unroll
                for (int mi = 0; mi < 2; mi++)
#pragma unroll
                    for (int nj = 0; nj < 8; nj++)
                        acc2[mi][nj] = __builtin_amdgcn_mfma_f32_16x16x32_bf16(aF[mi], bF[nj], acc2[mi][nj], 0, 0, 0);
            }
            __syncthreads();
        }
    }
    // ---- epilogue: per-thread weighted atomic scatter (CSR-sorted rows) ----
#pragma unroll
    for (int mi = 0; mi < 2; mi++) {
        int rbase = w * 32 + mi * 16 + q * 4;
        int n0 = nid[rbase], n3 = nid[rbase + 3];
        float c0v = cf[rbase], c1v = cf[rbase + 1], c2v = cf[rbase + 2], c3v = cf[rbase + 3];
#pragma unroll
        for (int nj = 0; nj < 8; nj++) {
            int col = nj * 16 + lr;
            float b = bvec[col];
            if (n0 == n3) {
                if (n0 >= 0) {
                    float s = c0v * (acc2[mi][nj][0] + b) + c1v * (acc2[mi][nj][1] + b)
                            + c2v * (acc2[mi][nj][2] + b) + c3v * (acc2[mi][nj][3] + b);
                    atomicAdd(&out_acc[(size_t)n0 * FD + col], s);
                }
            } else {
                int n1 = nid[rbase + 1], n2 = nid[rbase + 2];
                if (n0 >= 0) atomicAdd(&out_acc[(size_t)n0 * FD + col], c0v * (acc2[mi][nj][0] + b));
                if (n1 >= 0) atomicAdd(&out_acc[(size_t)n1 * FD + col], c1v * (acc2[mi][nj][1] + b));
                if (n2 >= 0) atomicAdd(&out_acc[(size_t)n2 * FD + col], c2v * (acc2[mi][nj][2] + b));
                if (n3 >= 0) atomicAdd(&out_acc[(size_t)n3 * FD + col], c3v * (acc2[mi][nj][3] + b));
            }
        }
    }
}

// =================== final (in place): out = out/3 + x ===================
__global__ void k_finalout(float* __restrict__ out, const float* __restrict__ x) {
    int i = blockIdx.x * 256 + threadIdx.x;
    if (i < NN * FD) out[i] = fin(out[i]) * (1.f / 3.f) + x[i];
}

extern "C" void kernel_launch(void* const* d_in, const int* in_sizes, int n_in,
                              void* d_out, int out_size, void* d_ws, size_t ws_size,
                              hipStream_t stream) {
    const float* ew   = (const float*)d_in[0];
    const float* x    = (const float*)d_in[1];
    const float* gW1  = (const float*)d_in[2];
    const float* gg   = (const float*)d_in[4];
    const float* gbe  = (const float*)d_in[5];
    const float* gWo  = (const float*)d_in[6];
    const float* gbo  = (const float*)d_in[7];
    const float* mW1  = (const float*)d_in[8];
    const float* mg   = (const float*)d_in[10];
    const float* mbe  = (const float*)d_in[11];
    const float* mWo  = (const float*)d_in[12];
    const float* mbo  = (const float*)d_in[13];
    const float* powp = (const float*)d_in[14];
    const int* self_idx = (const int*)d_in[15];
    const int* nbr_idx  = (const int*)d_in[16];
    float* out = (float*)d_out;

    char* ws = (char*)d_ws;
    size_t off = 0;
    auto alloc = [&](size_t bytes) -> void* {
        size_t o = off;
        off += (bytes + 255) & ~(size_t)255;
        return (void*)(ws + o);
    };

    // ---- zero span (contiguous) ----
    float* S       = (float*)alloc(256 * 256 * 4);
    float* colsum  = (float*)alloc(512 * 4);
    int*   cnt     = (int*)alloc((size_t)NN * 4);
    int*   cntn    = (int*)alloc((size_t)NN * 4);
    int*   fill    = (int*)alloc((size_t)NN * 4);
    size_t zero_end = off;
    // ---- rest ----
    unsigned short* xb   = (unsigned short*)alloc((size_t)NN * FD * 2);
    unsigned short* W1t  = (unsigned short*)alloc(6ull * 65536 * 2);
    unsigned short* Wo2t = (unsigned short*)alloc(3ull * 32768 * 2);
    float* scaleA = (float*)alloc(6ull * 256 * 4);
    float* shiftA = (float*)alloc(6ull * 256 * 4);
    int*   rp     = (int*)alloc((size_t)(NN + 1) * 4);
    int*   pincl  = (int*)alloc((size_t)NN * 4);
    int*   bsum   = (int*)alloc(512 * 4);
    int*   boff   = (int*)alloc(512 * 4);
    int*   elist  = (int*)alloc((size_t)MM * 4);
    int*   selfp  = (int*)alloc((size_t)MM * 4);
    int*   nbrp   = (int*)alloc((size_t)MM * 4);
    float* glog   = (float*)alloc(3ull * MM * 4);
    float* coef   = (float*)alloc(3ull * MM * 4);
    if (off > ws_size) return;   // ~47 MB needed

    int zwords = (int)(zero_end / 4);
    k_zero<<<(zwords + 255) / 256, 256, 0, stream>>>(S, zwords);
    k_zero<<<(NN * FD + 255) / 256, 256, 0, stream>>>(out, NN * FD);  // out = accumulator

    k_castx<<<(NN * FD / 2 + 255) / 256, 256, 0, stream>>>(x, xb);
    k_transpose_w1<<<1536, 256, 0, stream>>>(gW1, mW1, W1t);
    k_transpose_wo<<<384, 256, 0, stream>>>(mWo, Wo2t);

    k_hist<<<1954, 256, 0, stream>>>(self_idx, cnt);
    k_hist<<<1954, 256, 0, stream>>>(nbr_idx, cntn);
    int nb1 = (NN + 255) / 256;   // 391
    k_scan1<<<nb1, 256, 0, stream>>>(cnt, pincl, bsum);
    k_scan2<<<1, 512, 0, stream>>>(bsum, boff, nb1);
    k_scan3<<<nb1, 256, 0, stream>>>(pincl, boff, rp);
    k_scatter<<<1954, 256, 0, stream>>>(self_idx, rp, fill, elist);
    k_perm<<<1954, 256, 0, stream>>>(elist, self_idx, nbr_idx, selfp, nbrp);

    k_colsum<<<(NN + 511) / 512, 256, 0, stream>>>(x, cnt, cntn, colsum);
    k_S<<<dim3(128, 4), 256, 0, stream>>>(xb, self_idx, nbr_idx, S);
    k_stats<<<dim3(16, 6), 256, 0, stream>>>(S, colsum, W1t, gg, gbe, mg, mbe, scaleA, shiftA);

    for (int h = 0; h < 3; h++)
        k_gate<<<NTILES, 256, 0, stream>>>(xb, selfp, nbrp, W1t + (size_t)h * 65536,
                                           scaleA + h * 256, shiftA + h * 256,
                                           gWo + h * 256, gbo + h, glog + (size_t)h * MM);
    k_coef<<<nb1, 256, 0, stream>>>(rp, glog, coef, ew, nbrp, powp);
    for (int h = 0; h < 3; h++) {
        int j = 3 + h;
        k_msg<<<NTILES, 256, 0, stream>>>(xb, selfp, nbrp, W1t + (size_t)j * 65536,
                                          scaleA + j * 256, shiftA + j * 256,
                                          Wo2t + (size_t)h * 32768, mbo + h * 128,
                                          coef + (size_t)h * MM, out);
    }
    k_finalout<<<(NN * FD + 255) / 256, 256, 0, stream>>>(out, x);
}